// Round 4
// baseline (1115.700 us; speedup 1.0000x reference)
//
#include <hip/hip_runtime.h>

// Problem constants (match reference)
#define BATCH 8
#define NPTS  32768
#define DIM   256
#define NSAMP 64      // NPOINT (fps samples)
#define NNBR  8       // ball-query neighbors
#define LN_EPS 1e-5f

// FPS working-set split (32 slices of 1024 points each):
//   slices [0, K_LDS)     -> LDS (144 KB, loaded once)
//   slices [K_LDS, 32)    -> streamed from L2 each iteration as float4
// R2/R3 lesson: the compiler allocates 64 VGPRs for this kernel regardless of
// __launch_bounds__ headroom, so any per-thread state beyond ~64 regs spills
// to scratch (VGPR_Count=64 both rounds). Fix: design the live set to fit 64 —
// no register-resident coord slices; dist[32] + transients only (~55 regs).
#define K_LDS    12
#define K_STREAM 20   // 20480 points = 5120 float4-groups = 5 groups/thread

// Inter-kernel buffers as device globals (no d_ws dependence).
__device__ float g_sample_coor[BATCH * NSAMP * 3];
__device__ float g_diff_coor[BATCH * NSAMP * 3];
__device__ float g_qbuf[BATCH * NSAMP * DIM];
__device__ float g_kbuf[BATCH * NSAMP * DIM];
__device__ int   g_fidx[BATCH * NSAMP];

// I/O dtypes (forensically established):
//  - inputs  = FLOAT32 storage (R2: reading as bf16 created sNaN patterns -> NaN)
//  - outputs = FLOAT32 storage (bf16 ushort writes gave deterministic 6.72 error)
// FPS distance precision: f32 direct form (dx*dx+dy*dy+dz*dz) — verified
// passing in R2/R3; do NOT algebraically refactor (rounding flips argmax).
// Ball-query keeps f64 distances (radius threshold compare, unchanged).

__device__ __forceinline__ double dist2_64(float px, float py, float pz,
                                           float cx, float cy, float cz) {
    double dx = (double)px - (double)cx;
    double dy = (double)py - (double)cy;
    double dz = (double)pz - (double)cz;
    return (dx * dx + dy * dy) + dz * dz;   // numpy's (x^2+y^2)+z^2 order
}

// ============================================================================
// Kernel A: farthest-point sampling. One block per batch (R1 showed cross-XCD
// barriers cost ~37us/iter — never again). 1024 threads, 32 points/thread.
// 12 slices resident in LDS; 20 slices streamed from L2 via float4 (4 points
// per 3xfloat4). dist[] in f32 regs. Argmax tie-break: lowest index
// (strict >, ascending-p processing order preserved under the remapping:
// streamed point for dist[12+4j+i] is STRM0 + 4*(j*1024+t) + i, ascending in
// (j,i) for fixed t).
// ============================================================================
__global__ __launch_bounds__(1024, 4)
__attribute__((amdgpu_waves_per_eu(4, 4)))
void fps_kernel(const float* __restrict__ coor)
{
    const int b = blockIdx.x;
    const int t = threadIdx.x;
    const float* cb = coor + (size_t)b * NPTS * 3;

    __shared__ float s_coor[K_LDS][1024][3];   // 144 KB (gfx950: 160 KB/WG max)
    __shared__ float s_rv[16];
    __shared__ int   s_ri[16];
    __shared__ float s_ctr[3];

    // one-time staging: LDS slices
#pragma unroll
    for (int k = 0; k < K_LDS; ++k) {
        const int p = (k << 10) + t;
        s_coor[k][t][0] = cb[p * 3 + 0];
        s_coor[k][t][1] = cb[p * 3 + 1];
        s_coor[k][t][2] = cb[p * 3 + 2];
    }

    float dist[32];
#pragma unroll
    for (int k = 0; k < 32; ++k) dist[k] = 1e10f;

    // streamed region base, as float4 (16B-aligned: 12288*12B = 147456B)
    const float4* cb4 = (const float4*)(cb + 3 * (K_LDS << 10));

    float cx = cb[0], cy = cb[1], cz = cb[2];
    int cidx = 0;                       // only meaningful on t==0
    __syncthreads();

    for (int s = 0; s < NSAMP; ++s) {
        if (t == 0) {
            g_fidx[b * NSAMP + s] = cidx;
            g_sample_coor[(b * NSAMP + s) * 3 + 0] = cx;
            g_sample_coor[(b * NSAMP + s) * 3 + 1] = cy;
            g_sample_coor[(b * NSAMP + s) * 3 + 2] = cz;
        }
        if (s == NSAMP - 1) break;

        float best = -1.0f; int bidx = 0;

        // ---- LDS slices (p ascending) ----
#pragma unroll
        for (int k = 0; k < K_LDS; ++k) {
            float dx = s_coor[k][t][0] - cx;
            float dy = s_coor[k][t][1] - cy;
            float dz = s_coor[k][t][2] - cz;
            float d2 = dx * dx + dy * dy + dz * dz;
            float nd = fminf(dist[k], d2);
            dist[k] = nd;
            if (nd > best) { best = nd; bidx = (k << 10) + t; }
        }
        // ---- streamed slices: 5 groups of 4 points via 3x float4 ----
#pragma unroll 2
        for (int j = 0; j < 5; ++j) {
            const int g = (j << 10) + t;          // group index
            const float4 v0 = cb4[g * 3 + 0];
            const float4 v1 = cb4[g * 3 + 1];
            const float4 v2 = cb4[g * 3 + 2];
            const float qx[4] = { v0.x, v0.w, v1.z, v2.y };
            const float qy[4] = { v0.y, v1.x, v1.w, v2.z };
            const float qz[4] = { v0.z, v1.y, v2.x, v2.w };
            const int pbase = (K_LDS << 10) + (g << 2);
#pragma unroll
            for (int i = 0; i < 4; ++i) {
                float dx = qx[i] - cx, dy = qy[i] - cy, dz = qz[i] - cz;
                float d2 = dx * dx + dy * dy + dz * dz;
                const int di = K_LDS + (j << 2) + i;
                float nd = fminf(dist[di], d2);
                dist[di] = nd;
                if (nd > best) { best = nd; bidx = pbase + i; }
            }
        }

        // ---- wave butterfly argmax, lowest-index tie-break (f32) ----
#pragma unroll
        for (int off = 32; off > 0; off >>= 1) {
            float ov = __shfl_xor(best, off);
            int   oi = __shfl_xor(bidx, off);
            if (ov > best || (ov == best && oi < bidx)) { best = ov; bidx = oi; }
        }
        if ((t & 63) == 0) { s_rv[t >> 6] = best; s_ri[t >> 6] = bidx; }
        __syncthreads();

        // ---- wave-0 16-lane butterfly over the per-wave partials ----
        if (t < 64) {
            float bv = (t < 16) ? s_rv[t] : -2.0f;     // real dists >= 0
            int   bi = (t < 16) ? s_ri[t] : 0x7fffffff;
#pragma unroll
            for (int off = 8; off > 0; off >>= 1) {
                float ov = __shfl_xor(bv, off);
                int   oi = __shfl_xor(bi, off);
                if (ov > bv || (ov == bv && oi < bi)) { bv = ov; bi = oi; }
            }
            if (t == 0) {
                cidx = bi;
                s_ctr[0] = cb[bi * 3 + 0];
                s_ctr[1] = cb[bi * 3 + 1];
                s_ctr[2] = cb[bi * 3 + 2];
            }
        }
        __syncthreads();
        cx = s_ctr[0]; cy = s_ctr[1]; cz = s_ctr[2];
    }
}

// ============================================================================
// Kernel B: ball query (first-8 within radius by index order, f64 distance,
// early exit) + grouped-feature max (out0 = global_x, f32) + diff_coor mean.
// One wave per (b,s) center.
// ============================================================================
__global__ __launch_bounds__(64) void ballquery_kernel(
    const float* __restrict__ coor,
    const float* __restrict__ x,
    float* __restrict__ out0)
{
    const int bid = blockIdx.x;
    const int b = bid >> 6, s = bid & 63;
    const int lane = threadIdx.x;
    const float* cb = coor + (size_t)b * NPTS * 3;

    const float cx = g_sample_coor[(b * NSAMP + s) * 3 + 0];
    const float cy = g_sample_coor[(b * NSAMP + s) * 3 + 1];
    const float cz = g_sample_coor[(b * NSAMP + s) * 3 + 2];

    __shared__ int s_nidx[NNBR];
    int found = 0;
    for (int ch = 0; ch < NPTS / 64 && found < NNBR; ++ch) {
        int p = (ch << 6) + lane;
        double d2 = dist2_64(cb[p * 3 + 0], cb[p * 3 + 1], cb[p * 3 + 2],
                             cx, cy, cz);
        unsigned long long m = __ballot(d2 < 16.0);   // strict <
        while (m && found < NNBR) {                   // wave-uniform
            int bpos = __ffsll(m) - 1;
            if (lane == 0) s_nidx[found] = (ch << 6) + bpos;
            ++found;
            m &= m - 1;
        }
    }
    if (lane == 0) {                         // pad with first hit (or 0 if none)
        if (found == 0) { s_nidx[0] = 0; found = 1; }
        int f0 = s_nidx[0];
        for (int j = found; j < NNBR; ++j) s_nidx[j] = f0;
    }
    __syncthreads();

    // grouped-feature max -> out0 (4 channels/lane; f32 in, f32 out)
    int c0 = lane * 4;
    float a0 = -1e30f, a1 = -1e30f, a2 = -1e30f, a3 = -1e30f;
#pragma unroll
    for (int j = 0; j < NNBR; ++j) {
        const float4 v = *(const float4*)(x + ((size_t)b * NPTS + s_nidx[j]) * DIM + c0);
        a0 = fmaxf(a0, v.x); a1 = fmaxf(a1, v.y);
        a2 = fmaxf(a2, v.z); a3 = fmaxf(a3, v.w);
    }
    float4 o; o.x = a0; o.y = a1; o.z = a2; o.w = a3;
    *(float4*)(out0 + ((size_t)(b * NSAMP + s)) * DIM + c0) = o;

    // diff_coor = mean_j (p_j - c)   (continuous path)
    if (lane < 3) {
        float sum = 0.f;
#pragma unroll
        for (int j = 0; j < NNBR; ++j) {
            float pv = cb[s_nidx[j] * 3 + lane];
            sum += pv - ((lane == 0) ? cx : (lane == 1) ? cy : cz);
        }
        g_diff_coor[(b * NSAMP + s) * 3 + lane] = sum * 0.125f;
    }
}

// ============================================================================
// Kernel C1: LayerNorm + row @ W^T. One block per (b, s, which) row.
// which==0: q from diff_x = global_x(out0) - sample_x ; which==1: k from sample_x.
// ============================================================================
__global__ __launch_bounds__(256) void ln_gemm_kernel(
    const float* __restrict__ x,
    const float* __restrict__ out0,
    const float* __restrict__ Wq,
    const float* __restrict__ Wk,
    const float* __restrict__ gq, const float* __restrict__ bq,
    const float* __restrict__ gk, const float* __restrict__ bk)
{
    const int bid = blockIdx.x;
    const int which = bid & 1;
    const int s = (bid >> 1) & 63;
    const int b = bid >> 7;
    const int c = threadIdx.x;

    const int fidx = g_fidx[b * NSAMP + s];
    float xs = x[((size_t)b * NPTS + fidx) * DIM + c];
    float r  = which ? xs : (out0[(size_t)(b * NSAMP + s) * DIM + c] - xs);

    __shared__ float red[4];
    __shared__ float ln[DIM];

    float sum = r;
#pragma unroll
    for (int off = 32; off; off >>= 1) sum += __shfl_xor(sum, off);
    int wid = c >> 6;
    if ((c & 63) == 0) red[wid] = sum;
    __syncthreads();
    float mean = (red[0] + red[1] + red[2] + red[3]) * (1.0f / DIM);
    float d = r - mean;
    float vs = d * d;
#pragma unroll
    for (int off = 32; off; off >>= 1) vs += __shfl_xor(vs, off);
    __syncthreads();
    if ((c & 63) == 0) red[wid] = vs;
    __syncthreads();
    float var = (red[0] + red[1] + red[2] + red[3]) * (1.0f / DIM);
    float rs = 1.0f / sqrtf(var + LN_EPS);

    ln[c] = d * rs * (which ? gk[c] : gq[c]) + (which ? bk[c] : bq[c]);
    __syncthreads();

    const float* W = (which ? Wk : Wq) + (size_t)c * DIM;
    float acc = 0.f;
#pragma unroll 4
    for (int i = 0; i < DIM; i += 4) {
        float4 wv = *(const float4*)(W + i);      // 16B aligned
        acc = fmaf(ln[i + 0], wv.x, acc);
        acc = fmaf(ln[i + 1], wv.y, acc);
        acc = fmaf(ln[i + 2], wv.z, acc);
        acc = fmaf(ln[i + 3], wv.w, acc);
    }
    (which ? g_kbuf : g_qbuf)[(size_t)(b * NSAMP + s) * DIM + c] = acc;
}

// ============================================================================
// Kernel C2: attention per batch: logits (64x64) -> softmax -> @v -> out1.
// v is the [B,3,S]->[B,S,3] memory reinterpretation of diff_coor.
// ============================================================================
__global__ __launch_bounds__(1024) void attn_kernel(
    float* __restrict__ out1)
{
    const int b = blockIdx.x;
    const int tid = threadIdx.x;
    __shared__ float att[64][64];
    __shared__ float vv[64][3];

    // logits: thread computes row i, cols j0..j0+3
    {
        const int i  = tid >> 4;
        const int j0 = (tid & 15) << 2;
        const float* qr = g_qbuf + (size_t)(b * NSAMP + i) * DIM;
        const float* k0 = g_kbuf + (size_t)(b * NSAMP + j0) * DIM;
        float a0 = 0, a1 = 0, a2 = 0, a3 = 0;
        for (int ii = 0; ii < DIM; ii += 4) {
            float4 qv = *(const float4*)(qr + ii);
            float4 v0 = *(const float4*)(k0 + ii);
            float4 v1 = *(const float4*)(k0 + DIM + ii);
            float4 v2 = *(const float4*)(k0 + 2 * DIM + ii);
            float4 v3 = *(const float4*)(k0 + 3 * DIM + ii);
            a0 += qv.x * v0.x + qv.y * v0.y + qv.z * v0.z + qv.w * v0.w;
            a1 += qv.x * v1.x + qv.y * v1.y + qv.z * v1.z + qv.w * v1.w;
            a2 += qv.x * v2.x + qv.y * v2.y + qv.z * v2.z + qv.w * v2.w;
            a3 += qv.x * v3.x + qv.y * v3.y + qv.z * v3.z + qv.w * v3.w;
        }
        att[i][j0 + 0] = a0 * 0.0625f;   // scale = 1/sqrt(256)
        att[i][j0 + 1] = a1 * 0.0625f;
        att[i][j0 + 2] = a2 * 0.0625f;
        att[i][j0 + 3] = a3 * 0.0625f;
    }
    __syncthreads();

    const int wv_ = tid >> 6, lane = tid & 63;
    // softmax rows (wave per row, 4 rows/wave)
    for (int r = wv_; r < 64; r += 16) {
        float v = att[r][lane];
        float m = v;
#pragma unroll
        for (int off = 32; off; off >>= 1) m = fmaxf(m, __shfl_xor(m, off));
        float e = expf(v - m);
        float ss = e;
#pragma unroll
        for (int off = 32; off; off >>= 1) ss += __shfl_xor(ss, off);
        att[r][lane] = e / ss;
    }
    // build v: flat t = m*3+d reads diff_coor[b, t%64, t/64]
    if (tid < 192) {
        int m = tid / 3, d = tid - 3 * m;
        vv[m][d] = g_diff_coor[(size_t)(b * NSAMP + (tid & 63)) * 3 + (tid >> 6)];
    }
    __syncthreads();

    // coor_2 = attn @ v ; out1 = sample_coor + coor_2  (f32 out)
    for (int r = wv_; r < 64; r += 16) {
        float a = att[r][lane];
        float s0 = a * vv[lane][0];
        float s1 = a * vv[lane][1];
        float s2 = a * vv[lane][2];
#pragma unroll
        for (int off = 32; off; off >>= 1) {
            s0 += __shfl_xor(s0, off);
            s1 += __shfl_xor(s1, off);
            s2 += __shfl_xor(s2, off);
        }
        if (lane == 0) {
            int o = (b * NSAMP + r) * 3;
            out1[o + 0] = g_sample_coor[o + 0] + s0;
            out1[o + 1] = g_sample_coor[o + 1] + s1;
            out1[o + 2] = g_sample_coor[o + 2] + s2;
        }
    }
}

// ============================================================================
extern "C" void kernel_launch(void* const* d_in, const int* in_sizes, int n_in,
                              void* d_out, int out_size, void* d_ws, size_t ws_size,
                              hipStream_t stream)
{
    const float* x    = (const float*)d_in[0];
    const float* coor = (const float*)d_in[1];
    if (in_sizes[0] == BATCH * NPTS * 3) {   // defensive size-based resolution
        x    = (const float*)d_in[1];
        coor = (const float*)d_in[0];
    }
    const float* Wq   = (const float*)d_in[2];
    const float* Wk   = (const float*)d_in[3];
    const float* gq   = (const float*)d_in[4];
    const float* bq   = (const float*)d_in[5];
    const float* gk   = (const float*)d_in[6];
    const float* bk   = (const float*)d_in[7];

    float* out0 = (float*)d_out;                          // [B,S,C] f32
    float* out1 = out0 + (size_t)BATCH * NSAMP * DIM;     // [B,S,3] f32

    hipLaunchKernelGGL(fps_kernel, dim3(BATCH), dim3(1024), 0, stream, coor);
    hipLaunchKernelGGL(ballquery_kernel, dim3(BATCH * NSAMP), dim3(64), 0, stream,
                       coor, x, out0);
    hipLaunchKernelGGL(ln_gemm_kernel, dim3(BATCH * NSAMP * 2), dim3(256), 0, stream,
                       x, out0, Wq, Wk, gq, bq, gk, bk);
    hipLaunchKernelGGL(attn_kernel, dim3(BATCH), dim3(1024), 0, stream, out1);
}

// Round 5
// 870.011 us; speedup vs baseline: 1.2824x; 1.2824x over previous
//
#include <hip/hip_runtime.h>

// Problem constants (match reference)
#define BATCH 8
#define NPTS  32768
#define DIM   256
#define NSAMP 64      // NPOINT (fps samples)
#define NNBR  8       // ball-query neighbors
#define LN_EPS 1e-5f

// FPS working-set split (32 slices of 1024 points each):
//   slices [0, K_LDS)   -> LDS (156 KB, loaded once)
//   slices [K_LDS, 32)  -> streamed from L2 each iteration (scalar loads)
// R2/R3/R4 lesson: compiler gives this kernel <=64 VGPRs regardless of bounds
// hints; attribute pins made it WORSE (R4: 52 regs, 1MB scratch->HBM/iter).
// Design rule: live set must fit ~50 regs -> dist[32] + transients only.
#define K_LDS    13
#define K_STREAM 19

// Inter-kernel buffers as device globals (no d_ws dependence).
__device__ float g_sample_coor[BATCH * NSAMP * 3];
__device__ float g_diff_coor[BATCH * NSAMP * 3];
__device__ float g_qbuf[BATCH * NSAMP * DIM];
__device__ float g_kbuf[BATCH * NSAMP * DIM];
__device__ int   g_fidx[BATCH * NSAMP];
// ball-query bitmask: bit p of g_bmask[center][ch] = (point ch*64+p within radius)
__device__ unsigned long long g_bmask[BATCH * NSAMP][NPTS / 64];   // 2 MB

// I/O dtypes (forensically established):
//  - inputs  = FLOAT32 storage; outputs = FLOAT32 storage.
// FPS distance precision: f32 direct form (dx*dx+dy*dy+dz*dz) — verified
// passing in R2/R3/R4; do NOT algebraically refactor (rounding flips argmax).
// Ball-query keeps f64 distances (radius threshold compare, unchanged).

__device__ __forceinline__ double dist2_64(float px, float py, float pz,
                                           float cx, float cy, float cz) {
    double dx = (double)px - (double)cx;
    double dy = (double)py - (double)cy;
    double dz = (double)pz - (double)cz;
    return (dx * dx + dy * dy) + dz * dz;   // numpy's (x^2+y^2)+z^2 order
}

// ============================================================================
// Kernel A: farthest-point sampling. One block per batch (R1: cross-XCD
// barriers cost ~37us/iter — never again). 1024 threads, 32 points/thread.
// 13 slices resident in LDS (156 KB); 19 streamed from L2 (scalar loads —
// R4's float4 remap backfired). dist[] in f32 regs (~48 live regs, no spill).
// Reduce: ONE barrier/iter; partials parity-double-buffered; every wave
// redundantly reduces the 16 partials (same strict->/lowest-index tie-break).
// ============================================================================
__global__ __launch_bounds__(1024) void fps_kernel(
    const float* __restrict__ coor)
{
    const int b = blockIdx.x;
    const int t = threadIdx.x;
    const float* cb = coor + (size_t)b * NPTS * 3;

    __shared__ float s_coor[K_LDS][1024][3];   // 156 KB (gfx950 pool: 160 KB)
    __shared__ float s_rv[2][16];
    __shared__ int   s_ri[2][16];

    // one-time staging: LDS slices
#pragma unroll
    for (int k = 0; k < K_LDS; ++k) {
        const int p = (k << 10) + t;
        s_coor[k][t][0] = cb[p * 3 + 0];
        s_coor[k][t][1] = cb[p * 3 + 1];
        s_coor[k][t][2] = cb[p * 3 + 2];
    }

    float dist[32];
#pragma unroll
    for (int k = 0; k < 32; ++k) dist[k] = 1e10f;

    float cx = cb[0], cy = cb[1], cz = cb[2];
    int cidx = 0;                       // block-uniform winner index
    __syncthreads();

    for (int s = 0; s < NSAMP; ++s) {
        if (t == 0) {
            g_fidx[b * NSAMP + s] = cidx;
            g_sample_coor[(b * NSAMP + s) * 3 + 0] = cx;
            g_sample_coor[(b * NSAMP + s) * 3 + 1] = cy;
            g_sample_coor[(b * NSAMP + s) * 3 + 2] = cz;
        }
        if (s == NSAMP - 1) break;

        float best = -1.0f; int bidx = 0;

        // ---- LDS slices (p ascending) ----
#pragma unroll
        for (int k = 0; k < K_LDS; ++k) {
            float dx = s_coor[k][t][0] - cx;
            float dy = s_coor[k][t][1] - cy;
            float dz = s_coor[k][t][2] - cz;
            float d2 = dx * dx + dy * dy + dz * dz;
            float nd = fminf(dist[k], d2);
            dist[k] = nd;
            if (nd > best) { best = nd; bidx = (k << 10) + t; }
        }
        // ---- streamed slices (L2-resident after iter 0; scalar loads) ----
#pragma unroll 4
        for (int k = 0; k < K_STREAM; ++k) {
            const int p = ((K_LDS + k) << 10) + t;
            float sx = cb[p * 3 + 0];
            float sy = cb[p * 3 + 1];
            float sz = cb[p * 3 + 2];
            float dx = sx - cx, dy = sy - cy, dz = sz - cz;
            float d2 = dx * dx + dy * dy + dz * dz;
            float nd = fminf(dist[K_LDS + k], d2);
            dist[K_LDS + k] = nd;
            if (nd > best) { best = nd; bidx = p; }
        }

        // ---- wave butterfly argmax, lowest-index tie-break (f32) ----
#pragma unroll
        for (int off = 32; off > 0; off >>= 1) {
            float ov = __shfl_xor(best, off);
            int   oi = __shfl_xor(bidx, off);
            if (ov > best || (ov == best && oi < bidx)) { best = ov; bidx = oi; }
        }
        const int par = s & 1;
        if ((t & 63) == 0) { s_rv[par][t >> 6] = best; s_ri[par][t >> 6] = bidx; }
        __syncthreads();
        // every wave reduces the 16 partials itself (no second barrier; parity
        // double-buffer makes the single barrier race-free across iterations)
        float bv = s_rv[par][t & 15];
        int   bi = s_ri[par][t & 15];
#pragma unroll
        for (int off = 8; off > 0; off >>= 1) {
            float ov = __shfl_xor(bv, off);
            int   oi = __shfl_xor(bi, off);
            if (ov > bv || (ov == bv && oi < bi)) { bv = ov; bi = oi; }
        }
        // all lanes now hold the block winner
        cidx = bi;
        const int sl = bi >> 10, ix = bi & 1023;
        if (sl < K_LDS) {
            cx = s_coor[sl][ix][0];
            cy = s_coor[sl][ix][1];
            cz = s_coor[sl][ix][2];
        } else {
            cx = cb[bi * 3 + 0];
            cy = cb[bi * 3 + 1];
            cz = cb[bi * 3 + 2];
        }
    }
}

// ============================================================================
// Kernel B1: ball-query mask build. One wave per (batch, chunk-of-64-points):
// loads 64 points ONCE, loops the 64 centers computing the f64 in-radius
// ballot, stores one u64 mask per (center, chunk). Removes the old kernel's
// serial load->ballot->branch chain (FPS centers are extreme points, so the
// old early-exit often scanned most of the 512 chunks at ~400cyc each).
// ============================================================================
__global__ __launch_bounds__(64) void ballmask_kernel(
    const float* __restrict__ coor)
{
    const int bid = blockIdx.x;          // b * 512 + ch
    const int b   = bid >> 9;
    const int ch  = bid & 511;
    const int lane = threadIdx.x;
    const float* cb = coor + (size_t)b * NPTS * 3;

    const int p = (ch << 6) + lane;
    const float px = cb[p * 3 + 0];
    const float py = cb[p * 3 + 1];
    const float pz = cb[p * 3 + 2];

    const float* sc = g_sample_coor + b * NSAMP * 3;
#pragma unroll 4
    for (int s = 0; s < NSAMP; ++s) {
        double d2 = dist2_64(px, py, pz, sc[s * 3 + 0], sc[s * 3 + 1],
                             sc[s * 3 + 2]);
        unsigned long long m = __ballot(d2 < 16.0);   // strict <
        if (lane == 0) g_bmask[b * NSAMP + s][ch] = m;
    }
}

// ============================================================================
// Kernel B2: gather first-8 in-radius neighbors from the bitmask (ascending
// (chunk, bit) order == ascending point index — bit-identical semantics to
// the old serial scan, including first-hit padding), then grouped-feature
// max (out0) + diff_coor mean. One wave per (b,s) center.
// ============================================================================
__global__ __launch_bounds__(64) void ballgather_kernel(
    const float* __restrict__ coor,
    const float* __restrict__ x,
    float* __restrict__ out0)
{
    const int bid = blockIdx.x;
    const int b = bid >> 6, s = bid & 63;
    const int lane = threadIdx.x;
    const float* cb = coor + (size_t)b * NPTS * 3;

    const float cx = g_sample_coor[(b * NSAMP + s) * 3 + 0];
    const float cy = g_sample_coor[(b * NSAMP + s) * 3 + 1];
    const float cz = g_sample_coor[(b * NSAMP + s) * 3 + 2];

    __shared__ int s_nidx[NNBR];
    const unsigned long long* mrow = g_bmask[b * NSAMP + s];

    int found = 0;
    for (int g = 0; g < (NPTS / 64) / 64 && found < NNBR; ++g) {
        unsigned long long mym = mrow[(g << 6) + lane];       // lane's chunk
        unsigned long long nz = __ballot(mym != 0ull);        // chunks with hits
        while (nz && found < NNBR) {                          // wave-uniform
            int src = __ffsll(nz) - 1;                        // lowest chunk
            unsigned long long mv = __shfl(mym, src);
            int pbase = (((g << 6) + src) << 6);
            while (mv && found < NNBR) {
                int bpos = __ffsll(mv) - 1;
                if (lane == 0) s_nidx[found] = pbase + bpos;
                ++found;
                mv &= mv - 1;
            }
            nz &= nz - 1;
        }
    }
    if (lane == 0) {                         // pad with first hit (or 0 if none)
        if (found == 0) { s_nidx[0] = 0; found = 1; }
        int f0 = s_nidx[0];
        for (int j = found; j < NNBR; ++j) s_nidx[j] = f0;
    }
    __syncthreads();

    // grouped-feature max -> out0 (4 channels/lane; f32 in, f32 out)
    int c0 = lane * 4;
    float a0 = -1e30f, a1 = -1e30f, a2 = -1e30f, a3 = -1e30f;
#pragma unroll
    for (int j = 0; j < NNBR; ++j) {
        const float4 v = *(const float4*)(x + ((size_t)b * NPTS + s_nidx[j]) * DIM + c0);
        a0 = fmaxf(a0, v.x); a1 = fmaxf(a1, v.y);
        a2 = fmaxf(a2, v.z); a3 = fmaxf(a3, v.w);
    }
    float4 o; o.x = a0; o.y = a1; o.z = a2; o.w = a3;
    *(float4*)(out0 + ((size_t)(b * NSAMP + s)) * DIM + c0) = o;

    // diff_coor = mean_j (p_j - c)   (continuous path)
    if (lane < 3) {
        float sum = 0.f;
#pragma unroll
        for (int j = 0; j < NNBR; ++j) {
            float pv = cb[s_nidx[j] * 3 + lane];
            sum += pv - ((lane == 0) ? cx : (lane == 1) ? cy : cz);
        }
        g_diff_coor[(b * NSAMP + s) * 3 + lane] = sum * 0.125f;
    }
}

// ============================================================================
// Kernel C1: LayerNorm + row @ W^T. One block per (b, s, which) row.
// which==0: q from diff_x = global_x(out0) - sample_x ; which==1: k from sample_x.
// ============================================================================
__global__ __launch_bounds__(256) void ln_gemm_kernel(
    const float* __restrict__ x,
    const float* __restrict__ out0,
    const float* __restrict__ Wq,
    const float* __restrict__ Wk,
    const float* __restrict__ gq, const float* __restrict__ bq,
    const float* __restrict__ gk, const float* __restrict__ bk)
{
    const int bid = blockIdx.x;
    const int which = bid & 1;
    const int s = (bid >> 1) & 63;
    const int b = bid >> 7;
    const int c = threadIdx.x;

    const int fidx = g_fidx[b * NSAMP + s];
    float xs = x[((size_t)b * NPTS + fidx) * DIM + c];
    float r  = which ? xs : (out0[(size_t)(b * NSAMP + s) * DIM + c] - xs);

    __shared__ float red[4];
    __shared__ float ln[DIM];

    float sum = r;
#pragma unroll
    for (int off = 32; off; off >>= 1) sum += __shfl_xor(sum, off);
    int wid = c >> 6;
    if ((c & 63) == 0) red[wid] = sum;
    __syncthreads();
    float mean = (red[0] + red[1] + red[2] + red[3]) * (1.0f / DIM);
    float d = r - mean;
    float vs = d * d;
#pragma unroll
    for (int off = 32; off; off >>= 1) vs += __shfl_xor(vs, off);
    __syncthreads();
    if ((c & 63) == 0) red[wid] = vs;
    __syncthreads();
    float var = (red[0] + red[1] + red[2] + red[3]) * (1.0f / DIM);
    float rs = 1.0f / sqrtf(var + LN_EPS);

    ln[c] = d * rs * (which ? gk[c] : gq[c]) + (which ? bk[c] : bq[c]);
    __syncthreads();

    const float* W = (which ? Wk : Wq) + (size_t)c * DIM;
    float acc = 0.f;
#pragma unroll 4
    for (int i = 0; i < DIM; i += 4) {
        float4 wv = *(const float4*)(W + i);      // 16B aligned
        acc = fmaf(ln[i + 0], wv.x, acc);
        acc = fmaf(ln[i + 1], wv.y, acc);
        acc = fmaf(ln[i + 2], wv.z, acc);
        acc = fmaf(ln[i + 3], wv.w, acc);
    }
    (which ? g_kbuf : g_qbuf)[(size_t)(b * NSAMP + s) * DIM + c] = acc;
}

// ============================================================================
// Kernel C2: attention per batch: logits (64x64) -> softmax -> @v -> out1.
// v is the [B,3,S]->[B,S,3] memory reinterpretation of diff_coor.
// ============================================================================
__global__ __launch_bounds__(1024) void attn_kernel(
    float* __restrict__ out1)
{
    const int b = blockIdx.x;
    const int tid = threadIdx.x;
    __shared__ float att[64][64];
    __shared__ float vv[64][3];

    // logits: thread computes row i, cols j0..j0+3
    {
        const int i  = tid >> 4;
        const int j0 = (tid & 15) << 2;
        const float* qr = g_qbuf + (size_t)(b * NSAMP + i) * DIM;
        const float* k0 = g_kbuf + (size_t)(b * NSAMP + j0) * DIM;
        float a0 = 0, a1 = 0, a2 = 0, a3 = 0;
        for (int ii = 0; ii < DIM; ii += 4) {
            float4 qv = *(const float4*)(qr + ii);
            float4 v0 = *(const float4*)(k0 + ii);
            float4 v1 = *(const float4*)(k0 + DIM + ii);
            float4 v2 = *(const float4*)(k0 + 2 * DIM + ii);
            float4 v3 = *(const float4*)(k0 + 3 * DIM + ii);
            a0 += qv.x * v0.x + qv.y * v0.y + qv.z * v0.z + qv.w * v0.w;
            a1 += qv.x * v1.x + qv.y * v1.y + qv.z * v1.z + qv.w * v1.w;
            a2 += qv.x * v2.x + qv.y * v2.y + qv.z * v2.z + qv.w * v2.w;
            a3 += qv.x * v3.x + qv.y * v3.y + qv.z * v3.z + qv.w * v3.w;
        }
        att[i][j0 + 0] = a0 * 0.0625f;   // scale = 1/sqrt(256)
        att[i][j0 + 1] = a1 * 0.0625f;
        att[i][j0 + 2] = a2 * 0.0625f;
        att[i][j0 + 3] = a3 * 0.0625f;
    }
    __syncthreads();

    const int wv_ = tid >> 6, lane = tid & 63;
    // softmax rows (wave per row, 4 rows/wave)
    for (int r = wv_; r < 64; r += 16) {
        float v = att[r][lane];
        float m = v;
#pragma unroll
        for (int off = 32; off; off >>= 1) m = fmaxf(m, __shfl_xor(m, off));
        float e = expf(v - m);
        float ss = e;
#pragma unroll
        for (int off = 32; off; off >>= 1) ss += __shfl_xor(ss, off);
        att[r][lane] = e / ss;
    }
    // build v: flat t = m*3+d reads diff_coor[b, t%64, t/64]
    if (tid < 192) {
        int m = tid / 3, d = tid - 3 * m;
        vv[m][d] = g_diff_coor[(size_t)(b * NSAMP + (tid & 63)) * 3 + (tid >> 6)];
    }
    __syncthreads();

    // coor_2 = attn @ v ; out1 = sample_coor + coor_2  (f32 out)
    for (int r = wv_; r < 64; r += 16) {
        float a = att[r][lane];
        float s0 = a * vv[lane][0];
        float s1 = a * vv[lane][1];
        float s2 = a * vv[lane][2];
#pragma unroll
        for (int off = 32; off; off >>= 1) {
            s0 += __shfl_xor(s0, off);
            s1 += __shfl_xor(s1, off);
            s2 += __shfl_xor(s2, off);
        }
        if (lane == 0) {
            int o = (b * NSAMP + r) * 3;
            out1[o + 0] = g_sample_coor[o + 0] + s0;
            out1[o + 1] = g_sample_coor[o + 1] + s1;
            out1[o + 2] = g_sample_coor[o + 2] + s2;
        }
    }
}

// ============================================================================
extern "C" void kernel_launch(void* const* d_in, const int* in_sizes, int n_in,
                              void* d_out, int out_size, void* d_ws, size_t ws_size,
                              hipStream_t stream)
{
    const float* x    = (const float*)d_in[0];
    const float* coor = (const float*)d_in[1];
    if (in_sizes[0] == BATCH * NPTS * 3) {   // defensive size-based resolution
        x    = (const float*)d_in[1];
        coor = (const float*)d_in[0];
    }
    const float* Wq   = (const float*)d_in[2];
    const float* Wk   = (const float*)d_in[3];
    const float* gq   = (const float*)d_in[4];
    const float* bq   = (const float*)d_in[5];
    const float* gk   = (const float*)d_in[6];
    const float* bk   = (const float*)d_in[7];

    float* out0 = (float*)d_out;                          // [B,S,C] f32
    float* out1 = out0 + (size_t)BATCH * NSAMP * DIM;     // [B,S,3] f32

    hipLaunchKernelGGL(fps_kernel, dim3(BATCH), dim3(1024), 0, stream, coor);
    hipLaunchKernelGGL(ballmask_kernel, dim3(BATCH * (NPTS / 64)), dim3(64), 0,
                       stream, coor);
    hipLaunchKernelGGL(ballgather_kernel, dim3(BATCH * NSAMP), dim3(64), 0, stream,
                       coor, x, out0);
    hipLaunchKernelGGL(ln_gemm_kernel, dim3(BATCH * NSAMP * 2), dim3(256), 0, stream,
                       x, out0, Wq, Wk, gq, bq, gk, bk);
    hipLaunchKernelGGL(attn_kernel, dim3(BATCH), dim3(1024), 0, stream, out1);
}